// Round 3
// baseline (330.603 us; speedup 1.0000x reference)
//
#include <hip/hip_runtime.h>
#include <math.h>

#define NTOK 8192
#define HID  4096
#define NEXP 64
#define TOPK 8

typedef float f4 __attribute__((ext_vector_type(4)));

// ---- FMA helpers: acc indices are compile-time constants (no dynamic arrays) ----
#define ACC1(E, WV)                              \
    acc[E] = fmaf(hv.x, (WV).x, acc[E]);         \
    acc[E] = fmaf(hv.y, (WV).y, acc[E]);         \
    acc[E] = fmaf(hv.z, (WV).z, acc[E]);         \
    acc[E] = fmaf(hv.w, (WV).w, acc[E]);

#define FMA8(EB, B0,B1,B2,B3,B4,B5,B6,B7)        \
    { ACC1((EB)+0, B0) ACC1((EB)+1, B1) ACC1((EB)+2, B2) ACC1((EB)+3, B3) \
      ACC1((EB)+4, B4) ACC1((EB)+5, B5) ACC1((EB)+6, B6) ACC1((EB)+7, B7) }

#define WL8(P, B0,B1,B2,B3,B4,B5,B6,B7)          \
    { const float* _p = (P);                     \
      B0 = *(const f4*)(_p + 0*HID);             \
      B1 = *(const f4*)(_p + 1*HID);             \
      B2 = *(const f4*)(_p + 2*HID);             \
      B3 = *(const f4*)(_p + 3*HID);             \
      B4 = *(const f4*)(_p + 4*HID);             \
      B5 = *(const f4*)(_p + 5*HID);             \
      B6 = *(const f4*)(_p + 6*HID);             \
      B7 = *(const f4*)(_p + 7*HID); }

// =====================================================================
// Kernel 1: partial logits.  grid = 128*M blocks x 256 threads.
// block b: g = b/M (64 tokens), m = b%M (macro k-slice).
// wave w: k-sub-slice base = (m*4+w)*SL, SL = HID/(4M).  lane = token.
// acc[64] = per-expert partial dot.  Deterministic fixed-order sums.
// =====================================================================
__global__ __launch_bounds__(256, 2)
void k1_partial(const float* __restrict__ Hm, const float* __restrict__ Wm,
                float* __restrict__ ws, int M)
{
    __shared__ f4 LB[4096];                 // 64 KB: staging (32KB) then reduce (64KB)

    const int tid  = threadIdx.x;
    const int wave = tid >> 6;
    const int lane = tid & 63;
    const int g    = blockIdx.x / M;
    const int m    = blockIdx.x % M;
    const int tok0 = g * 64;

    const int SL    = HID / (4 * M);        // k per wave
    const int NCH   = SL / 32;              // 32-k chunks
    const int KTOT  = SL / 4;               // kq steps
    const int kbase = (m * 4 + wave) * SL;

    f4* hTw = LB + wave * 512;              // per-wave 8KB h tile [kq(8)][tok(64)] f4

    // staging identities: lane -> (row, colq); 8 rows per instr, coalesced per 8 lanes
    const int srow = lane >> 3;             // 0..7
    const int scol = lane & 7;              // 0..7
    const f4* hp = (const f4*)Hm + (size_t)(tok0 + srow) * (HID / 4) + (kbase >> 2) + scol;
    const int stw = scol * 64 + srow;       // hT f4 index for i=0

    const float* wk = Wm + kbase;

    float acc[64];
#pragma unroll
    for (int e = 0; e < 64; ++e) acc[e] = 0.f;

    // ---- prologue: h chunk 0 -> named regs ----
    f4 h0 = hp[0*8192], h1 = hp[1*8192], h2 = hp[2*8192], h3 = hp[3*8192],
       h4 = hp[4*8192], h5 = hp[5*8192], h6 = hp[6*8192], h7 = hp[7*8192];

    // ---- prologue: W bufs a <- (kq0, e0..7), b <- (kq0, e8..15) ----
    f4 a0,a1,a2,a3,a4,a5,a6,a7, b0,b1,b2,b3,b4,b5,b6,b7;
    WL8(wk,           a0,a1,a2,a3,a4,a5,a6,a7)
    WL8(wk + 8*HID,   b0,b1,b2,b3,b4,b5,b6,b7)

    int kqg = 0;
#pragma unroll 1
    for (int ch = 0; ch < NCH; ++ch) {
        // stage current chunk regs -> LDS (transposed [kq][tok])
        hTw[stw +  0] = h0;  hTw[stw +  8] = h1;
        hTw[stw + 16] = h2;  hTw[stw + 24] = h3;
        hTw[stw + 32] = h4;  hTw[stw + 40] = h5;
        hTw[stw + 48] = h6;  hTw[stw + 56] = h7;

        // prefetch next chunk (wrap harmless, always in-row)
        {
            const int chn = (ch + 1 == NCH) ? 0 : ch + 1;
            const f4* hq = hp + chn * 8;
            h0 = hq[0*8192]; h1 = hq[1*8192]; h2 = hq[2*8192]; h3 = hq[3*8192];
            h4 = hq[4*8192]; h5 = hq[5*8192]; h6 = hq[6*8192]; h7 = hq[7*8192];
        }

#pragma unroll 1
        for (int kq8 = 0; kq8 < 8; ++kq8) {
            const f4 hv = hTw[kq8 * 64 + lane];
            const float* pk = wk + kqg * 4;
            const int kqn = (kqg + 1 == KTOT) ? 0 : kqg + 1;
            const float* pn = wk + kqn * 4;

            // 8-step, 2-buffer rolling pipeline (use buf loaded 2 steps ago)
            FMA8( 0, a0,a1,a2,a3,a4,a5,a6,a7)  WL8(pk + 16*HID, a0,a1,a2,a3,a4,a5,a6,a7)
            FMA8( 8, b0,b1,b2,b3,b4,b5,b6,b7)  WL8(pk + 24*HID, b0,b1,b2,b3,b4,b5,b6,b7)
            FMA8(16, a0,a1,a2,a3,a4,a5,a6,a7)  WL8(pk + 32*HID, a0,a1,a2,a3,a4,a5,a6,a7)
            FMA8(24, b0,b1,b2,b3,b4,b5,b6,b7)  WL8(pk + 40*HID, b0,b1,b2,b3,b4,b5,b6,b7)
            FMA8(32, a0,a1,a2,a3,a4,a5,a6,a7)  WL8(pk + 48*HID, a0,a1,a2,a3,a4,a5,a6,a7)
            FMA8(40, b0,b1,b2,b3,b4,b5,b6,b7)  WL8(pk + 56*HID, b0,b1,b2,b3,b4,b5,b6,b7)
            FMA8(48, a0,a1,a2,a3,a4,a5,a6,a7)  WL8(pn,          a0,a1,a2,a3,a4,a5,a6,a7)
            FMA8(56, b0,b1,b2,b3,b4,b5,b6,b7)  WL8(pn + 8*HID,  b0,b1,b2,b3,b4,b5,b6,b7)
            ++kqg;
        }
    }

    // ---- cross-wave reduce (fixed order w=0..3) ----
    __syncthreads();                        // all waves done with staging regions
#pragma unroll
    for (int q = 0; q < 16; ++q) {
        f4 v;
        v.x = acc[q*4+0]; v.y = acc[q*4+1]; v.z = acc[q*4+2]; v.w = acc[q*4+3];
        LB[wave*1024 + lane*16 + (q ^ (lane & 7))] = v;   // swizzled, conflict-min
    }
    __syncthreads();

    f4* wsf4 = (f4*)ws;
#pragma unroll
    for (int j = 0; j < 4; ++j) {
        const int s    = tid + 256 * j;     // logical slot: tok*16 + q
        const int tokL = s >> 4;
        const int q    = s & 15;
        const int ph   = tokL*16 + (q ^ (tokL & 7));
        f4 v = LB[ph];
        v += LB[1024 + ph];
        v += LB[2048 + ph];
        v += LB[3072 + ph];
        wsf4[((size_t)m * NTOK + tok0 + tokL) * 16 + q] = v;
    }
}

// =====================================================================
// Kernel 2: fixed-order macro reduce + softmax + top-8 (R1-proven epilogue).
// grid = NTOK/16 blocks x 64 threads; lane = expert.
// =====================================================================
__global__ __launch_bounds__(64, 4)
void k2_finish(const float* __restrict__ ws, float* __restrict__ out, int M)
{
    const int lane = threadIdx.x & 63;
    float* outw = out;
    float* outi = out + (size_t)NTOK * TOPK;

    for (int t = 0; t < 16; ++t) {
        const int tok = blockIdx.x * 16 + t;
        float logit = 0.f;
#pragma unroll 1
        for (int mm = 0; mm < M; ++mm)
            logit += ws[((size_t)mm * NTOK + tok) * 64 + lane];

        float mx = logit;
#pragma unroll
        for (int off = 32; off; off >>= 1) mx = fmaxf(mx, __shfl_xor(mx, off));
        const float pv = expf(logit - mx);
        float ss = pv;
#pragma unroll
        for (int off = 32; off; off >>= 1) ss += __shfl_xor(ss, off);
        float v = pv / ss;

#pragma unroll
        for (int kk = 0; kk < TOPK; ++kk) {
            float bv = v;
            int   bi = lane;
#pragma unroll
            for (int off = 32; off; off >>= 1) {
                const float ov = __shfl_xor(bv, off);
                const int   oi = __shfl_xor(bi, off);
                if (ov > bv || (ov == bv && oi < bi)) { bv = ov; bi = oi; }
            }
            if (lane == kk) {
                outw[(size_t)tok * TOPK + kk] = bv;
                outi[(size_t)tok * TOPK + kk] = (float)bi;
            }
            if (lane == bi) v = -INFINITY;
        }
    }
}

extern "C" void kernel_launch(void* const* d_in, const int* in_sizes, int n_in,
                              void* d_out, int out_size, void* d_ws, size_t ws_size,
                              hipStream_t stream) {
    (void)in_sizes; (void)n_in; (void)out_size;
    const float* h = (const float*)d_in[0];   // [8192, 4096] fp32
    const float* w = (const float*)d_in[1];   // [64, 4096]  fp32
    float* out = (float*)d_out;               // weights (65536 f32) ++ indices (65536 as f32)
    float* ws  = (float*)d_ws;

    const size_t need4 = (size_t)4 * NTOK * NEXP * sizeof(float);  // 8 MB
    const int M = (ws_size >= need4) ? 4 : (ws_size >= need4 / 2) ? 2 : 1;

    k1_partial<<<128 * M, 256, 0, stream>>>(h, w, ws, M);
    k2_finish<<<NTOK / 16, 64, 0, stream>>>(ws, out, M);
}

// Round 4
// 175.207 us; speedup vs baseline: 1.8869x; 1.8869x over previous
//
#include <hip/hip_runtime.h>
#include <math.h>
#include <stdint.h>

#define NTOK 8192
#define HID  4096
#define NEXP 64
#define TOPK 8

typedef float f4 __attribute__((ext_vector_type(4)));

constexpr int MSPLIT = 4;           // K-split across blocks
constexpr int KB     = HID / MSPLIT;   // 1024 k per block
constexpr int CHK    = 64;          // k per staged chunk
constexpr int NCH    = KB / CHK;    // 16 chunks
// LDS per buffer: H 64tok x 64k x 4B = 16KB (4096 floats), W same. 2 buffers = 64KB.

__device__ __forceinline__ void gll16(const float* g, float* l) {
    __builtin_amdgcn_global_load_lds(
        (const __attribute__((address_space(1))) uint32_t*)g,
        (__attribute__((address_space(3))) uint32_t*)l, 16, 0, 0);
}

// =====================================================================
// k1: partial logits. grid = 128*4 blocks x 256 thr.
// block: 64 tokens x 64 experts x 1024 k. Waves split each chunk's 16
// k-quad slots {4w..4w+3}. Per-lane tile: 8 tok x 8 exp (acc[8][8]).
// LDS slot s (1KB) holds, for row r (token/expert=lane), k-quad s^(r&7)
// -- swizzle applied on the GLOBAL source address, LDS dest linear.
// =====================================================================
__global__ __launch_bounds__(256, 2)
void k1_partial(const float* __restrict__ Hm, const float* __restrict__ Wm,
                float* __restrict__ ws)
{
    __shared__ float lds[2 * 8192];

    const int tid  = threadIdx.x;
    const int wave = tid >> 6;
    const int lane = tid & 63;
    const int tg   = lane >> 3;       // token group: tokens tg*8..tg*8+7
    const int eg   = lane & 7;        // expert group: experts eg*8..eg*8+7
    const int g    = blockIdx.x >> 2; // token-group id (0..127)
    const int m    = blockIdx.x & 3;  // k-slice id
    const int tok0 = g * 64;
    const int kb   = m * KB;

    // per-lane staging constants: this wave stages slots s = 4w+r (r=0..3)
    int q[4];
#pragma unroll
    for (int r = 0; r < 4; ++r) q[r] = ((4 * wave + r) ^ (lane & 7)) << 2;
    const float* hrow = Hm + (size_t)(tok0 + lane) * HID + kb;  // lane = token
    const float* wrow = Wm + (size_t)lane * HID + kb;           // lane = expert

    float acc[8][8] = {};

    // prologue: stage chunk 0 into buffer 0
#pragma unroll
    for (int r = 0; r < 4; ++r) {
        const int s = 4 * wave + r;
        gll16(hrow + q[r], &lds[s * 256]);
        gll16(wrow + q[r], &lds[4096 + s * 256]);
    }
    __syncthreads();

    for (int c = 0; c < NCH; ++c) {
        const int p = c & 1;
        // issue next chunk's loads into the other buffer (T3 minimum pipeline)
        if (c + 1 < NCH) {
            const int koff = (c + 1) * CHK;
#pragma unroll
            for (int r = 0; r < 4; ++r) {
                const int s = 4 * wave + r;
                gll16(hrow + koff + q[r], &lds[(p ^ 1) * 8192 + s * 256]);
                gll16(wrow + koff + q[r], &lds[(p ^ 1) * 8192 + 4096 + s * 256]);
            }
        }

        const float* Hb = &lds[p * 8192];
        const float* Wb = &lds[p * 8192 + 4096];
#pragma unroll
        for (int rstep = 0; rstep < 4; ++rstep) {
            const int kq = 4 * wave + rstep;   // this wave's k-quad slot
            f4 ha[8], wa[8];
#pragma unroll
            for (int i = 0; i < 8; ++i)
                ha[i] = *(const f4*)&Hb[((kq ^ i) << 8) + ((tg * 8 + i) << 2)];
#pragma unroll
            for (int j = 0; j < 8; ++j)
                wa[j] = *(const f4*)&Wb[((kq ^ j) << 8) + ((eg * 8 + j) << 2)];
#pragma unroll
            for (int i = 0; i < 8; ++i)
#pragma unroll
                for (int j = 0; j < 8; ++j) {
                    acc[i][j] = fmaf(ha[i].x, wa[j].x, acc[i][j]);
                    acc[i][j] = fmaf(ha[i].y, wa[j].y, acc[i][j]);
                    acc[i][j] = fmaf(ha[i].z, wa[j].z, acc[i][j]);
                    acc[i][j] = fmaf(ha[i].w, wa[j].w, acc[i][j]);
                }
        }
        __syncthreads();
    }

    // ---- cross-wave reduce (deterministic): A=lds[0..4095], B=lds[4096..8191]
    if (wave < 2) {
        float* R = &lds[wave * 4096];
#pragma unroll
        for (int i = 0; i < 8; ++i)
#pragma unroll
            for (int jq = 0; jq < 2; ++jq) {
                f4 v = {acc[i][jq * 4 + 0], acc[i][jq * 4 + 1],
                        acc[i][jq * 4 + 2], acc[i][jq * 4 + 3]};
                *(f4*)&R[(tg * 8 + i) * 64 + eg * 8 + jq * 4] = v;
            }
    }
    __syncthreads();
    if (wave >= 2) {
        float* R = &lds[(wave - 2) * 4096];
#pragma unroll
        for (int i = 0; i < 8; ++i)
#pragma unroll
            for (int jq = 0; jq < 2; ++jq) {
                f4 v = *(const f4*)&R[(tg * 8 + i) * 64 + eg * 8 + jq * 4];
                v.x += acc[i][jq * 4 + 0]; v.y += acc[i][jq * 4 + 1];
                v.z += acc[i][jq * 4 + 2]; v.w += acc[i][jq * 4 + 3];
                *(f4*)&R[(tg * 8 + i) * 64 + eg * 8 + jq * 4] = v;
            }
    }
    __syncthreads();

    // ---- final fold A+B -> ws[m][tok0..tok0+63][0..63]
    f4* wsf4 = (f4*)ws + ((size_t)m * NTOK + tok0) * 16;
#pragma unroll
    for (int u = 0; u < 4; ++u) {
        const int idx = tid * 4 + u;            // f4 index: tok*16 + quad
        f4 v = *(const f4*)&lds[idx * 4];
        const f4 vb = *(const f4*)&lds[4096 + idx * 4];
        v.x += vb.x; v.y += vb.y; v.z += vb.z; v.w += vb.w;
        wsf4[idx] = v;
    }
}

// =====================================================================
// k2: fixed-order macro reduce + softmax + top-8 (proven epilogue).
// grid = NTOK/16 x 64 threads; lane = expert.
// =====================================================================
__global__ __launch_bounds__(64, 4)
void k2_finish(const float* __restrict__ ws, float* __restrict__ out)
{
    const int lane = threadIdx.x & 63;
    float* outw = out;
    float* outi = out + (size_t)NTOK * TOPK;

    for (int t = 0; t < 16; ++t) {
        const int tok = blockIdx.x * 16 + t;
        float logit = 0.f;
#pragma unroll
        for (int mm = 0; mm < MSPLIT; ++mm)
            logit += ws[((size_t)mm * NTOK + tok) * 64 + lane];

        float mx = logit;
#pragma unroll
        for (int off = 32; off; off >>= 1) mx = fmaxf(mx, __shfl_xor(mx, off));
        const float pv = expf(logit - mx);
        float ss = pv;
#pragma unroll
        for (int off = 32; off; off >>= 1) ss += __shfl_xor(ss, off);
        float v = pv / ss;

#pragma unroll
        for (int kk = 0; kk < TOPK; ++kk) {
            float bv = v;
            int   bi = lane;
#pragma unroll
            for (int off = 32; off; off >>= 1) {
                const float ov = __shfl_xor(bv, off);
                const int   oi = __shfl_xor(bi, off);
                if (ov > bv || (ov == bv && oi < bi)) { bv = ov; bi = oi; }
            }
            if (lane == kk) {
                outw[(size_t)tok * TOPK + kk] = bv;
                outi[(size_t)tok * TOPK + kk] = (float)bi;
            }
            if (lane == bi) v = -INFINITY;
        }
    }
}

extern "C" void kernel_launch(void* const* d_in, const int* in_sizes, int n_in,
                              void* d_out, int out_size, void* d_ws, size_t ws_size,
                              hipStream_t stream) {
    (void)in_sizes; (void)n_in; (void)out_size; (void)ws_size;
    const float* h = (const float*)d_in[0];   // [8192, 4096] fp32
    const float* w = (const float*)d_in[1];   // [64, 4096]  fp32
    float* out = (float*)d_out;               // weights (65536 f32) ++ indices (65536 as f32)
    float* ws  = (float*)d_ws;                // 4 x 8192 x 64 f32 partials (8 MB)

    k1_partial<<<128 * MSPLIT, 256, 0, stream>>>(h, w, ws);
    k2_finish<<<NTOK / 16, 64, 0, stream>>>(ws, out);
}

// Round 5
// 93.481 us; speedup vs baseline: 3.5366x; 1.8742x over previous
//
#include <hip/hip_runtime.h>
#include <math.h>
#include <stdint.h>

#define NTOK 8192
#define HID  4096
#define NEXP 64
#define TOPK 8

typedef float    f32x4 __attribute__((ext_vector_type(4)));
typedef _Float16 f16x8 __attribute__((ext_vector_type(8)));
typedef _Float16 f16x4 __attribute__((ext_vector_type(4)));

// ---------------------------------------------------------------------
// k0: W fp32 -> (hi, lo) fp16, scaled by 2048 (exact pow2; undone in k2).
// ---------------------------------------------------------------------
__global__ __launch_bounds__(256)
void k0_wsplit(const float* __restrict__ W, _Float16* __restrict__ wh,
               _Float16* __restrict__ wl)
{
    const int i = blockIdx.x * 256 + threadIdx.x;      // f4 index, 65536 total
    const f32x4 x = ((const f32x4*)W)[i];
    f16x4 h4, l4;
#pragma unroll
    for (int u = 0; u < 4; ++u) {
        const float xs = x[u] * 2048.0f;
        const _Float16 hh = (_Float16)xs;
        h4[u] = hh;
        l4[u] = (_Float16)(xs - (float)hh);
    }
    ((f16x4*)wh)[i] = h4;
    ((f16x4*)wl)[i] = l4;
}

// ---------------------------------------------------------------------
// k1: logits (x2048) via fp16 split MFMA. 512 blocks x 64 thr (1 wave).
// Wave: 16 tokens x 64 experts x K=4096.  A: h fp32 converted in-reg.
// B: wh/wl fp16 streamed from L2.  No LDS, no barriers.
// ---------------------------------------------------------------------
__device__ __forceinline__ void cvt_hilo(f32x4 a, f32x4 b, f16x8& hi, f16x8& lo)
{
    float x[8] = {a.x, a.y, a.z, a.w, b.x, b.y, b.z, b.w};
#pragma unroll
    for (int j = 0; j < 8; ++j) {
        const _Float16 h = (_Float16)x[j];
        hi[j] = h;
        lo[j] = (_Float16)(x[j] - (float)h);
    }
}

#define LOADA(A0, A1, s) do { const float* _p = hptr + ((((s) & 127)) << 5); \
    A0 = *(const f32x4*)_p; A1 = *(const f32x4*)(_p + 4); } while (0)

#define LOADB(BH, BL, s) do { const int _o = (((s) & 127)) << 5;             \
    _Pragma("unroll")                                                        \
    for (int _e = 0; _e < 4; ++_e) {                                         \
        BH[_e] = *(const f16x8*)(whp[_e] + _o);                              \
        BL[_e] = *(const f16x8*)(wlp[_e] + _o);                              \
    } } while (0)

#define STEP(A0, A1, BH, BL) do { f16x8 _h, _l; cvt_hilo(A0, A1, _h, _l);    \
    _Pragma("unroll")                                                        \
    for (int _e = 0; _e < 4; ++_e) {                                         \
        acc[_e] = __builtin_amdgcn_mfma_f32_16x16x32_f16(_h, BH[_e], acc[_e], 0, 0, 0); \
        acc[_e] = __builtin_amdgcn_mfma_f32_16x16x32_f16(_h, BL[_e], acc[_e], 0, 0, 0); \
        acc[_e] = __builtin_amdgcn_mfma_f32_16x16x32_f16(_l, BH[_e], acc[_e], 0, 0, 0); \
    } } while (0)

__global__ __launch_bounds__(64)
void k1_logits(const float* __restrict__ Hm, const _Float16* __restrict__ wh,
               const _Float16* __restrict__ wl, float* __restrict__ lg)
{
    const int l    = threadIdx.x;       // 0..63
    const int row  = l & 15;            // A row / B col within tile
    const int kg   = l >> 4;            // k-subgroup (8 consecutive k)
    const int tok0 = blockIdx.x * 16;

    const float* hptr = Hm + (tok0 + row) * HID + kg * 8;
    const _Float16* whp[4];
    const _Float16* wlp[4];
#pragma unroll
    for (int e = 0; e < 4; ++e) {
        const int wr = (e * 16 + row) * HID + kg * 8;
        whp[e] = wh + wr;
        wlp[e] = wl + wr;
    }

    f32x4 acc[4];
#pragma unroll
    for (int e = 0; e < 4; ++e) acc[e] = (f32x4)(0.0f);

    // prefetch: A distance 4, B distance 2
    f32x4 Aa0, Aa1, Ab0, Ab1, Ac0, Ac1, Ad0, Ad1;
    f16x8 Bh0[4], Bl0[4], Bh1[4], Bl1[4];
    LOADA(Aa0, Aa1, 0); LOADA(Ab0, Ab1, 1); LOADA(Ac0, Ac1, 2); LOADA(Ad0, Ad1, 3);
    LOADB(Bh0, Bl0, 0); LOADB(Bh1, Bl1, 1);

#pragma unroll 1
    for (int s = 0; s < 128; s += 4) {
        STEP(Aa0, Aa1, Bh0, Bl0); LOADA(Aa0, Aa1, s + 4); LOADB(Bh0, Bl0, s + 2);
        STEP(Ab0, Ab1, Bh1, Bl1); LOADA(Ab0, Ab1, s + 5); LOADB(Bh1, Bl1, s + 3);
        STEP(Ac0, Ac1, Bh0, Bl0); LOADA(Ac0, Ac1, s + 6); LOADB(Bh0, Bl0, s + 4);
        STEP(Ad0, Ad1, Bh1, Bl1); LOADA(Ad0, Ad1, s + 7); LOADB(Bh1, Bl1, s + 5);
    }

    // C/D: col = lane&15 (expert), row = (lane>>4)*4 + reg (token)  [m89]
#pragma unroll
    for (int e4 = 0; e4 < 4; ++e4)
#pragma unroll
        for (int r = 0; r < 4; ++r) {
            const int tok = tok0 + kg * 4 + r;
            const int e   = e4 * 16 + row;
            lg[tok * 64 + e] = acc[e4][r];
        }
}

// ---------------------------------------------------------------------
// k2: softmax + top-8 by rank-count (no serial shfl chains).
// 512 blocks x 256 thr; wave = 1 token per iter, 4 iters.
// ---------------------------------------------------------------------
__global__ __launch_bounds__(256)
void k2_finish(const float* __restrict__ lg, float* __restrict__ out)
{
    __shared__ __align__(16) float sc[4][64];
    const int tid  = threadIdx.x;
    const int wave = tid >> 6;
    const int lane = tid & 63;
    float* outw = out;
    float* outi = out + (size_t)NTOK * TOPK;

    for (int t = 0; t < 4; ++t) {
        const int tok = blockIdx.x * 16 + wave * 4 + t;
        const float lgv = lg[tok * 64 + lane] * (1.0f / 2048.0f);

        float mx = lgv;
#pragma unroll
        for (int off = 32; off; off >>= 1) mx = fmaxf(mx, __shfl_xor(mx, off));
        const float p = expf(lgv - mx);
        float ss = p;
#pragma unroll
        for (int off = 32; off; off >>= 1) ss += __shfl_xor(ss, off);
        ss = __shfl(ss, 0);               // identical denominator on all lanes
        const float sval = p / ss;

        sc[wave][lane] = sval;
        __syncthreads();

        int rank = 0;
#pragma unroll
        for (int j4 = 0; j4 < 16; ++j4) {
            const f32x4 v = *(const f32x4*)&sc[wave][j4 * 4];
#pragma unroll
            for (int u = 0; u < 4; ++u) {
                const int j = j4 * 4 + u;
                rank += (v[u] > sval || (v[u] == sval && j < lane)) ? 1 : 0;
            }
        }
        if (rank < TOPK) {
            outw[(size_t)tok * TOPK + rank] = sval;
            outi[(size_t)tok * TOPK + rank] = (float)lane;
        }
        __syncthreads();
    }
}

extern "C" void kernel_launch(void* const* d_in, const int* in_sizes, int n_in,
                              void* d_out, int out_size, void* d_ws, size_t ws_size,
                              hipStream_t stream) {
    (void)in_sizes; (void)n_in; (void)out_size; (void)ws_size;
    const float* h = (const float*)d_in[0];   // [8192, 4096] fp32
    const float* w = (const float*)d_in[1];   // [64, 4096]  fp32
    float* out = (float*)d_out;

    _Float16* wh = (_Float16*)d_ws;                       // 512 KB
    _Float16* wl = wh + (size_t)NEXP * HID;               // 512 KB
    float*    lg = (float*)((char*)d_ws + (1 << 20));     // 2 MB logits (x2048)

    k0_wsplit<<<256, 256, 0, stream>>>(w, wh, wl);
    k1_logits<<<NTOK / 16, 64, 0, stream>>>(h, wh, wl, lg);
    k2_finish<<<NTOK / 16, 256, 0, stream>>>(lg, out);
}

// Round 6
// 88.874 us; speedup vs baseline: 3.7199x; 1.0518x over previous
//
#include <hip/hip_runtime.h>
#include <math.h>
#include <stdint.h>

#define NTOK 8192
#define HID  4096
#define NEXP 64
#define TOPK 8

typedef float    f32x4 __attribute__((ext_vector_type(4)));
typedef _Float16 f16x8 __attribute__((ext_vector_type(8)));
typedef _Float16 f16x4 __attribute__((ext_vector_type(4)));

// ---------------------------------------------------------------------
// k0: W fp32 -> (hi, lo) fp16, scaled by 2048 (exact pow2; undone in k2).
// ---------------------------------------------------------------------
__global__ __launch_bounds__(256)
void k0_wsplit(const float* __restrict__ W, _Float16* __restrict__ wh,
               _Float16* __restrict__ wl)
{
    const int i = blockIdx.x * 256 + threadIdx.x;      // f4 index, 65536 total
    const f32x4 x = ((const f32x4*)W)[i];
    f16x4 h4, l4;
#pragma unroll
    for (int u = 0; u < 4; ++u) {
        const float xs = x[u] * 2048.0f;
        const _Float16 hh = (_Float16)xs;
        h4[u] = hh;
        l4[u] = (_Float16)(xs - (float)hh);
    }
    ((f16x4*)wh)[i] = h4;
    ((f16x4*)wl)[i] = l4;
}

// ---------------------------------------------------------------------
// k1: logits (x2048) via fp16 split MFMA.
// 512 blocks x 256 thr (4 waves). All 4 waves: same 16 tokens, k-slice
// w*1024..w*1024+1023 (32 steps of 32k). LDS reduce -> lg[tok][e].
// acc split in 3 banks so the 12 MFMAs/step are independent chains.
// ---------------------------------------------------------------------
__device__ __forceinline__ void cvt_hilo(f32x4 a, f32x4 b, f16x8& hi, f16x8& lo)
{
    float x[8] = {a.x, a.y, a.z, a.w, b.x, b.y, b.z, b.w};
#pragma unroll
    for (int j = 0; j < 8; ++j) {
        const _Float16 h = (_Float16)x[j];
        hi[j] = h;
        lo[j] = (_Float16)(x[j] - (float)h);
    }
}

#define LOADA(A0, A1, s) do { const float* _p = hptr + ((((s) & 31)) << 5);  \
    A0 = *(const f32x4*)_p; A1 = *(const f32x4*)(_p + 4); } while (0)

#define LOADB(BH, BL, s) do { const int _o = (((s) & 31)) << 5;              \
    _Pragma("unroll")                                                        \
    for (int _e = 0; _e < 4; ++_e) {                                         \
        BH[_e] = *(const f16x8*)(whp[_e] + _o);                              \
        BL[_e] = *(const f16x8*)(wlp[_e] + _o);                              \
    } } while (0)

#define STEP(A0, A1, BH, BL) do { f16x8 _h, _l; cvt_hilo(A0, A1, _h, _l);    \
    _Pragma("unroll")                                                        \
    for (int _e = 0; _e < 4; ++_e) {                                         \
        accH[_e] = __builtin_amdgcn_mfma_f32_16x16x32_f16(_h, BH[_e], accH[_e], 0, 0, 0); \
        accM[_e] = __builtin_amdgcn_mfma_f32_16x16x32_f16(_h, BL[_e], accM[_e], 0, 0, 0); \
        accL[_e] = __builtin_amdgcn_mfma_f32_16x16x32_f16(_l, BH[_e], accL[_e], 0, 0, 0); \
    } } while (0)

__global__ __launch_bounds__(256, 2)
void k1_logits(const float* __restrict__ Hm, const _Float16* __restrict__ wh,
               const _Float16* __restrict__ wl, float* __restrict__ lg)
{
    __shared__ float red[4 * 1024];     // 16 KB: [wave][tok(16)][exp(64)]

    const int tid  = threadIdx.x;
    const int wave = tid >> 6;
    const int l    = tid & 63;
    const int row  = l & 15;            // A row / B col within tile
    const int kg   = l >> 4;            // k-subgroup (8 consecutive k)
    const int tok0 = blockIdx.x * 16;
    const int kb   = wave * (HID / 4);  // per-wave k-slice base

    const float* hptr = Hm + (size_t)(tok0 + row) * HID + kb + kg * 8;
    const _Float16* whp[4];
    const _Float16* wlp[4];
#pragma unroll
    for (int e = 0; e < 4; ++e) {
        const size_t wr = (size_t)(e * 16 + row) * HID + kb + kg * 8;
        whp[e] = wh + wr;
        wlp[e] = wl + wr;
    }

    f32x4 accH[4], accM[4], accL[4];
#pragma unroll
    for (int e = 0; e < 4; ++e) {
        accH[e] = (f32x4)(0.0f); accM[e] = (f32x4)(0.0f); accL[e] = (f32x4)(0.0f);
    }

    // prefetch: A distance 4, B distance 2
    f32x4 Aa0, Aa1, Ab0, Ab1, Ac0, Ac1, Ad0, Ad1;
    f16x8 Bh0[4], Bl0[4], Bh1[4], Bl1[4];
    LOADA(Aa0, Aa1, 0); LOADA(Ab0, Ab1, 1); LOADA(Ac0, Ac1, 2); LOADA(Ad0, Ad1, 3);
    LOADB(Bh0, Bl0, 0); LOADB(Bh1, Bl1, 1);

#pragma unroll 1
    for (int s = 0; s < 32; s += 4) {
        STEP(Aa0, Aa1, Bh0, Bl0); LOADA(Aa0, Aa1, s + 4); LOADB(Bh0, Bl0, s + 2);
        STEP(Ab0, Ab1, Bh1, Bl1); LOADA(Ab0, Ab1, s + 5); LOADB(Bh1, Bl1, s + 3);
        STEP(Ac0, Ac1, Bh0, Bl0); LOADA(Ac0, Ac1, s + 6); LOADB(Bh0, Bl0, s + 4);
        STEP(Ad0, Ad1, Bh1, Bl1); LOADA(Ad0, Ad1, s + 7); LOADB(Bh1, Bl1, s + 5);
    }

    // merge banks; C/D: col = lane&15 (expert), row = (lane>>4)*4 + reg (token)
#pragma unroll
    for (int e4 = 0; e4 < 4; ++e4) {
        const f32x4 a = accH[e4] + accM[e4] + accL[e4];
#pragma unroll
        for (int r = 0; r < 4; ++r)
            red[wave * 1024 + (kg * 4 + r) * 64 + e4 * 16 + row] = a[r];
    }
    __syncthreads();

    // cross-wave reduce (fixed order) + coalesced f4 store of final logits
    {
        const f32x4 v0 = *(const f32x4*)&red[tid * 4];
        const f32x4 v1 = *(const f32x4*)&red[1024 + tid * 4];
        const f32x4 v2 = *(const f32x4*)&red[2048 + tid * 4];
        const f32x4 v3 = *(const f32x4*)&red[3072 + tid * 4];
        ((f32x4*)lg)[(size_t)tok0 * 16 + tid] = (v0 + v1) + (v2 + v3);
    }
}

// ---------------------------------------------------------------------
// k2: softmax + top-8 by rank-count. 2048 blocks x 256 thr; 1 token/wave.
// ---------------------------------------------------------------------
__global__ __launch_bounds__(256)
void k2_finish(const float* __restrict__ lg, float* __restrict__ out)
{
    __shared__ __align__(16) float sc[4][64];
    const int tid  = threadIdx.x;
    const int wave = tid >> 6;
    const int lane = tid & 63;
    float* outw = out;
    float* outi = out + (size_t)NTOK * TOPK;

    const int tok = blockIdx.x * 4 + wave;
    const float lgv = lg[tok * 64 + lane] * (1.0f / 2048.0f);

    float mx = lgv;
#pragma unroll
    for (int off = 32; off; off >>= 1) mx = fmaxf(mx, __shfl_xor(mx, off));
    const float p = expf(lgv - mx);
    float ss = p;
#pragma unroll
    for (int off = 32; off; off >>= 1) ss += __shfl_xor(ss, off);
    ss = __shfl(ss, 0);               // identical denominator on all lanes
    const float sval = p / ss;

    sc[wave][lane] = sval;
    __syncthreads();

    int rank = 0;
#pragma unroll
    for (int j4 = 0; j4 < 16; ++j4) {
        const f32x4 v = *(const f32x4*)&sc[wave][j4 * 4];
#pragma unroll
        for (int u = 0; u < 4; ++u) {
            const int j = j4 * 4 + u;
            rank += (v[u] > sval || (v[u] == sval && j < lane)) ? 1 : 0;
        }
    }
    if (rank < TOPK) {
        outw[(size_t)tok * TOPK + rank] = sval;
        outi[(size_t)tok * TOPK + rank] = (float)lane;
    }
}

extern "C" void kernel_launch(void* const* d_in, const int* in_sizes, int n_in,
                              void* d_out, int out_size, void* d_ws, size_t ws_size,
                              hipStream_t stream) {
    (void)in_sizes; (void)n_in; (void)out_size; (void)ws_size;
    const float* h = (const float*)d_in[0];   // [8192, 4096] fp32
    const float* w = (const float*)d_in[1];   // [64, 4096]  fp32
    float* out = (float*)d_out;

    _Float16* wh = (_Float16*)d_ws;                       // 512 KB
    _Float16* wl = wh + (size_t)NEXP * HID;               // 512 KB
    float*    lg = (float*)((char*)d_ws + (1 << 20));     // 2 MB logits (x2048)

    k0_wsplit<<<256, 256, 0, stream>>>(w, wh, wl);
    k1_logits<<<NTOK / 16, 256, 0, stream>>>(h, wh, wl, lg);
    k2_finish<<<NTOK / 4, 256, 0, stream>>>(lg, out);
}

// Round 7
// 41.632 us; speedup vs baseline: 7.9411x; 2.1347x over previous
//
#include <hip/hip_runtime.h>
#include <math.h>
#include <stdint.h>

#define NTOK 8192
#define HID  4096
#define NEXP 64
#define TOPK 8

typedef float    f32x4 __attribute__((ext_vector_type(4)));
typedef _Float16 f16x8 __attribute__((ext_vector_type(8)));

// fp32x8 -> (hi, lo) fp16x8 split; W side is pre-scaled by 2048 by caller.
__device__ __forceinline__ void cvt_hilo(f32x4 a, f32x4 b, f16x8& hi, f16x8& lo)
{
    float x[8] = {a.x, a.y, a.z, a.w, b.x, b.y, b.z, b.w};
#pragma unroll
    for (int j = 0; j < 8; ++j) {
        const _Float16 h = (_Float16)x[j];
        hi[j] = h;
        lo[j] = (_Float16)(x[j] - (float)h);
    }
}

// ---------------------------------------------------------------------
// k1: partial logits (x2048) via fp16-split MFMA, B tile in LDS.
// grid = 512 blocks x 256 thr (4 waves).  block: tg = b>>2 (64 tokens),
// m = b&3 (k-quarter).  Wave w owns tokens tok0 = tg*64 + w*16.
// Per ktile (256 k): all 256 threads stage W fp32 -> hi/lo f16 into LDS
// (swizzled slot = c ^ (r&7) on BOTH write and read), barrier, then each
// wave runs 8 MFMA steps reading B from LDS, A from HBM (depth-4 named
// register ring, fully unrolled -> compile-time addresses).
// ---------------------------------------------------------------------
#define AL(SET, S) do { const float* _p = ha + (S) * 32;                     \
    SET##0 = *(const f32x4*)_p; SET##1 = *(const f32x4*)(_p + 4); } while (0)

#define STEPU(SET)  do { f16x8 _ah, _al; cvt_hilo(SET##0, SET##1, _ah, _al); \
    _Pragma("unroll")                                                        \
    for (int e4 = 0; e4 < 4; ++e4) {                                         \
        const int _r  = e4 * 16 + lr;                                        \
        const int _sl = ((ks * 4 + kg) ^ (_r & 7)) * 8;                      \
        const f16x8 _bh = *(const f16x8*)&whL[_r * 256 + _sl];               \
        const f16x8 _bl = *(const f16x8*)&wlL[_r * 256 + _sl];               \
        accH[e4] = __builtin_amdgcn_mfma_f32_16x16x32_f16(_ah, _bh, accH[e4], 0, 0, 0); \
        accM[e4] = __builtin_amdgcn_mfma_f32_16x16x32_f16(_ah, _bl, accM[e4], 0, 0, 0); \
        accL[e4] = __builtin_amdgcn_mfma_f32_16x16x32_f16(_al, _bh, accL[e4], 0, 0, 0); \
    } } while (0)

__global__ __launch_bounds__(256, 2)
void k1_partial(const float* __restrict__ Hm, const float* __restrict__ Wm,
                float* __restrict__ ws)
{
    __shared__ _Float16 whL[64 * 256];   // 32 KB  [expert r][256 k of ktile]
    __shared__ _Float16 wlL[64 * 256];   // 32 KB

    const int tid  = threadIdx.x;
    const int wave = tid >> 6;
    const int l    = tid & 63;
    const int lr   = l & 15;            // A row (token) / B col (expert) in tile
    const int kg   = l >> 4;            // k-subgroup (8 consecutive k)
    const int tg   = blockIdx.x >> 2;
    const int m    = blockIdx.x & 3;
    const int tok0 = tg * 64 + wave * 16;
    const int kb   = m * 1024;

    const float* ha = Hm + (size_t)(tok0 + lr) * HID + kb + kg * 8;

    f32x4 accH[4], accM[4], accL[4];
#pragma unroll
    for (int e = 0; e < 4; ++e) {
        accH[e] = (f32x4)(0.0f); accM[e] = (f32x4)(0.0f); accL[e] = (f32x4)(0.0f);
    }

    // A ring prologue: steps 0..3
    f32x4 Aa0, Aa1, Ab0, Ab1, Ac0, Ac1, Ad0, Ad1;
    AL(Aa, 0); AL(Ab, 1); AL(Ac, 2); AL(Ad, 3);

#pragma unroll
    for (int kt = 0; kt < 4; ++kt) {
        // ---- stage B ktile: W fp32 -> hi/lo f16, swizzled LDS write ----
#pragma unroll
        for (int t = 0; t < 8; ++t) {
            const int id = t * 256 + tid;       // 0..2047 = 64 rows x 32 chunks
            const int r  = id >> 5;
            const int c  = id & 31;
            const float* wp = Wm + (size_t)r * HID + kb + kt * 256 + c * 8;
            const f32x4 w0 = *(const f32x4*)wp;
            const f32x4 w1 = *(const f32x4*)(wp + 4);
            f16x8 hi, lo;
            cvt_hilo(w0 * 2048.0f, w1 * 2048.0f, hi, lo);
            const int sl = (c ^ (r & 7)) * 8;
            *(f16x8*)&whL[r * 256 + sl] = hi;
            *(f16x8*)&wlL[r * 256 + sl] = lo;
        }
        __syncthreads();

        // ---- 8 compute steps (k = kt*256 .. +255) ----
#pragma unroll
        for (int ks = 0; ks < 8; ++ks) {
            const int S = kt * 8 + ks;          // global step, compile-time
            if ((S & 3) == 0)      { STEPU(Aa); if (S + 4 < 32) AL(Aa, S + 4); }
            else if ((S & 3) == 1) { STEPU(Ab); if (S + 4 < 32) AL(Ab, S + 4); }
            else if ((S & 3) == 2) { STEPU(Ac); if (S + 4 < 32) AL(Ac, S + 4); }
            else                   { STEPU(Ad); if (S + 4 < 32) AL(Ad, S + 4); }
        }
        __syncthreads();                        // B tile dead before restage
    }

    // ---- merge banks, write own ws slice (no cross-wave reduce needed) ----
    float* wsw = ws + ((size_t)m * NTOK + tok0) * 64;
#pragma unroll
    for (int e4 = 0; e4 < 4; ++e4) {
        const f32x4 a = accH[e4] + accM[e4] + accL[e4];
#pragma unroll
        for (int r = 0; r < 4; ++r)
            wsw[(kg * 4 + r) * 64 + e4 * 16 + lr] = a[r];   // C/D: col=lane&15, row=(lane>>4)*4+r
    }
}

// ---------------------------------------------------------------------
// k2: fixed-order 4-slice reduce + softmax + top-8 rank-count.
// grid = 2048 x 256; 1 token per wave.
// ---------------------------------------------------------------------
__global__ __launch_bounds__(256)
void k2_finish(const float* __restrict__ ws, float* __restrict__ out)
{
    __shared__ __align__(16) float sc[4][64];
    const int tid  = threadIdx.x;
    const int wave = tid >> 6;
    const int lane = tid & 63;
    float* outw = out;
    float* outi = out + (size_t)NTOK * TOPK;

    const int tok = blockIdx.x * 4 + wave;
    const float* p = ws + (size_t)tok * 64 + lane;
    const float lgv = (((p[0] + p[(size_t)NTOK * 64])
                      + (p[(size_t)2 * NTOK * 64] + p[(size_t)3 * NTOK * 64])))
                      * (1.0f / 2048.0f);

    float mx = lgv;
#pragma unroll
    for (int off = 32; off; off >>= 1) mx = fmaxf(mx, __shfl_xor(mx, off));
    const float pv = expf(lgv - mx);
    float ss = pv;
#pragma unroll
    for (int off = 32; off; off >>= 1) ss += __shfl_xor(ss, off);
    ss = __shfl(ss, 0);                 // identical denominator on all lanes
    const float sval = pv / ss;

    sc[wave][lane] = sval;
    __syncthreads();

    int rank = 0;
#pragma unroll
    for (int j4 = 0; j4 < 16; ++j4) {
        const f32x4 v = *(const f32x4*)&sc[wave][j4 * 4];
#pragma unroll
        for (int u = 0; u < 4; ++u) {
            const int j = j4 * 4 + u;
            rank += (v[u] > sval || (v[u] == sval && j < lane)) ? 1 : 0;
        }
    }
    if (rank < TOPK) {
        outw[(size_t)tok * TOPK + rank] = sval;
        outi[(size_t)tok * TOPK + rank] = (float)lane;
    }
}

extern "C" void kernel_launch(void* const* d_in, const int* in_sizes, int n_in,
                              void* d_out, int out_size, void* d_ws, size_t ws_size,
                              hipStream_t stream) {
    (void)in_sizes; (void)n_in; (void)out_size; (void)ws_size;
    const float* h = (const float*)d_in[0];   // [8192, 4096] fp32
    const float* w = (const float*)d_in[1];   // [64, 4096]  fp32
    float* out = (float*)d_out;
    float* ws  = (float*)d_ws;                // [4][8192][64] f32 = 8 MB (proven fits)

    k1_partial<<<512, 256, 0, stream>>>(h, w, ws);
    k2_finish<<<NTOK / 4, 256, 0, stream>>>(ws, out);
}